// Round 1
// baseline (11.150 us; speedup 1.0000x reference)
//
#include <hip/hip_runtime.h>
#include <hip/hip_bf16.h>

// PCN_81647328297714
//
// Reference analysis: the scan's `cycle` only writes new[i] for i in
// range(1, L-1) = {1, 2}. s[3] (= state3) is carried through all 50
// cycles UNCHANGED, and the reference returns final[3]. Therefore the
// output is exactly state3 (d_in[6]) — all the GEMM/relu work is dead
// code w.r.t. the returned value.
//
// Confirmed empirically: the zero-output stub's absmax error was
// 2.209473e-02 == sqrt(2/4096) == max(state3) under its init.
//
// Input order (setup_inputs dict order):
//   d_in[0] = input_data (B*4096 f32)
//   d_in[1..3] = W1, W2, W3 (4096*4096 f32 each)
//   d_in[4..6] = state1, state2, state3 (B*4096 f32 each)
//   d_in[7] = batch_size (scalar)
//
// Output: out_size = B*4096 f32 elements = state3.

extern "C" void kernel_launch(void* const* d_in, const int* in_sizes, int n_in,
                              void* d_out, int out_size, void* d_ws, size_t ws_size,
                              hipStream_t stream) {
    const void* state3 = d_in[6];
    const size_t nbytes = (size_t)out_size * sizeof(float);
    hipMemcpyAsync(d_out, state3, nbytes, hipMemcpyDeviceToDevice, stream);
}

// Round 2
// 10.484 us; speedup vs baseline: 1.0635x; 1.0635x over previous
//
#include <hip/hip_runtime.h>
#include <hip/hip_bf16.h>

// PCN_81647328297714
//
// Reference analysis: the scan's `cycle` only writes new[i] for i in
// range(1, L-1) = {1, 2}. s[3] (= state3) is carried through all 50
// cycles UNCHANGED, and the reference returns final[3]. Therefore the
// output is exactly state3 (d_in[6]) — all GEMM/relu work is dead code
// w.r.t. the returned value. Verified: round-1 copy passed, absmax = 0.
//
// Round 2: replace hipMemcpyAsync (runtime blit path, 3.0 TB/s effective)
// with a dedicated float4 copy kernel targeting the ~6.3 TB/s D2D ceiling.
//
// out_size = 1024*4096 = 4,194,304 floats = 1,048,576 float4 (16 MiB).

__global__ __launch_bounds__(256) void copy_f4(const float4* __restrict__ src,
                                               float4* __restrict__ dst,
                                               int n4) {
    int i = blockIdx.x * blockDim.x + threadIdx.x;
    if (i < n4) dst[i] = src[i];
}

extern "C" void kernel_launch(void* const* d_in, const int* in_sizes, int n_in,
                              void* d_out, int out_size, void* d_ws, size_t ws_size,
                              hipStream_t stream) {
    const float4* state3 = (const float4*)d_in[6];
    float4* out = (float4*)d_out;
    int n4 = out_size / 4;  // out_size = 4,194,304 -> n4 = 1,048,576
    int block = 256;
    int grid = (n4 + block - 1) / block;  // 4096 blocks
    copy_f4<<<grid, block, 0, stream>>>(state3, out, n4);
}